// Round 13
// baseline (1158.979 us; speedup 1.0000x reference)
//
#include <hip/hip_runtime.h>
#include <math.h>

// Sizes: B=32 S=512 V=32000 D_IN=512 D_MODEL=2048 HEADS=8 HD=64
//        N_OUT=64 N_ACT=32 M=10 MH=64 T=20

typedef __attribute__((ext_vector_type(8))) short short8v;
typedef __attribute__((ext_vector_type(4))) float f32x4;

__device__ __forceinline__ float sigf(float x) { return 1.0f / (1.0f + __expf(-x)); }
__device__ __forceinline__ float decf(float d) { return __expf(-fminf(fmaxf(d, 0.0f), 15.0f)); }
// single-instruction packed f32->bf16 (RNE), gfx950
__device__ __forceinline__ unsigned int bf2(float lo, float hi) {
    unsigned int r;
    asm("v_cvt_pk_bf16_f32 %0, %1, %2" : "=v"(r) : "v"(lo), "v"(hi));
    return r;
}
__device__ __forceinline__ unsigned short bfr(float x) {
    return (unsigned short)(bf2(x, 0.0f) & 0xFFFFu);
}
__device__ __forceinline__ float bff(unsigned short u) {
    return __uint_as_float(((unsigned int)u) << 16);
}
#define BLO(u) __uint_as_float((u) << 16)
#define BHI(u) __uint_as_float((u) & 0xFFFF0000u)
__device__ __forceinline__ int SWZ(int byteoff) {
    return byteoff ^ (((byteoff >> 7) & 7) << 4);
}
// Wallt layout: [cg 0..255][kb 0..319][fr 0..15][ke 0..7]
__device__ __forceinline__ size_t wallt_idx(int c, int k) {
    const int cg = (c & 2047) >> 3;
    const int fr = (c & 7) + ((c < 2048) ? 0 : 8);
    return (((size_t)cg * 320 + (k >> 3)) * 16 + fr) * 8 + (k & 7);
}
// Abt layout (MFMA-native A): [kb 0..319][b 0..31][ke 0..7]
__device__ __forceinline__ size_t abt_idx(int b, int k) {
    return (((size_t)(k >> 3)) * 32 + b) * 8 + (k & 7);
}

// ---------------------------------------------------------------------------
// SETUP1: merged cheap setup work, branch by blockIdx:
//   [0,2841)     k0 init; [2841,2857) s3 bsyn2; [2857,3113) s4 Wallt[k>=512]
//   [3113,4137)  s5 NLM re-layout; [4137,4201) s6a M/qc0; [4201,4265) Winb
// ---------------------------------------------------------------------------
__global__ __launch_bounds__(256) void setup1(
    const float* __restrict__ st_tr, const float* __restrict__ st_ac,
    const int* __restrict__ iol, const int* __restrict__ ior,
    float* __restrict__ trace, float* __restrict__ act,
    unsigned short* __restrict__ Abt,
    float* __restrict__ aaB, float* __restrict__ baB,
    float* __restrict__ aoB, float* __restrict__ boB, float* __restrict__ stats,
    const float* __restrict__ Wsyn, unsigned short* __restrict__ Wallt,
    const float* __restrict__ battn, const float* __restrict__ bsyn,
    float* __restrict__ bsyn2,
    const float* __restrict__ W1, const float* __restrict__ b1,
    const float* __restrict__ W2,
    unsigned short* __restrict__ W1t, unsigned short* __restrict__ W2t,
    const float* __restrict__ Win, const float* __restrict__ b_in,
    const float* __restrict__ Wq, const float* __restrict__ bq,
    unsigned short* __restrict__ Mb, float* __restrict__ qc0,
    unsigned short* __restrict__ Winb)
{
    const int tid = threadIdx.x;
    const int bid = blockIdx.x;
    if (bid < 2841) {
        const int i = bid * 256 + tid;
        if (i < 655360) {
            const int n = i & 2047;
            const int m = (i >> 11) % 10;
            trace[i] = st_tr[n * 10 + m];
        } else if (i < 720896) {
            const int j = i - 655360;
            const int n = j & 2047, b = j >> 11;
            const float v = st_ac[n];
            act[j] = v;
            Abt[abt_idx(b, 512 + n)] = bfr(v);
        } else if (i < 721920) {
            aaB[i - 720896] = 0.0f;
        } else if (i < 722944) {
            baB[i - 721920] = 0.0f;
        } else if (i < 724992) {
            const int j = i - 722944;
            const int k = j & 63;
            aoB[j] = st_ac[iol[k]] * st_ac[ior[k]];
        } else if (i < 727040) {
            boB[i - 724992] = 1.0f;
        } else if (i < 727104) {
            stats[i - 727040] = 0.0f;
        }
    } else if (bid < 2857) {
        const int c = (bid - 2841) * 256 + tid;
        float s = bsyn[c];
        const float4* wr = (const float4*)(Wsyn + (size_t)c * 2560);
#pragma unroll 4
        for (int k4 = 0; k4 < 128; ++k4) {
            const float4 w = wr[k4];
            const float4 bb = *(const float4*)(battn + k4*4);
            s += w.x*bb.x + w.y*bb.y + w.z*bb.z + w.w*bb.w;
        }
        bsyn2[c] = s;
    } else if (bid < 3113) {
        // s4: one cg per block; writes fully coalesced in Wallt order
        const int cg = bid - 2857;
#pragma unroll
        for (int it = 0; it < 16; ++it) {
            const int flat = it * 256 + tid;        // unit = 8 elements
            const int kb_rel = flat >> 4;           // 0..255  -> kb = 64 + kb_rel
            const int fr = flat & 15;
            const int row = cg * 8 + (fr & 7) + ((fr >= 8) ? 2048 : 0);
            const int k0 = 512 + kb_rel * 8;
            const float4 v0 = *(const float4*)(Wsyn + (size_t)row * 2560 + k0);
            const float4 v1 = *(const float4*)(Wsyn + (size_t)row * 2560 + k0 + 4);
            uint4 o = { bf2(v0.x, v0.y), bf2(v0.z, v0.w), bf2(v1.x, v1.y), bf2(v1.z, v1.w) };
            *(uint4*)(Wallt + (((size_t)cg * 320 + 64 + kb_rel) * 16 + fr) * 8) = o;
        }
    } else if (bid < 4137) {
        const int t = (bid - 3113) * 256 + tid;
        const int n = t & 2047, hh = t >> 11;
        unsigned short tmp[16];
#pragma unroll
        for (int m = 0; m < 10; ++m) tmp[m] = bfr(W1[(size_t)(m * 128 + hh) * 2048 + n]);
        tmp[10] = bfr(b1[n * 128 + hh]);
        tmp[11] = 0; tmp[12] = 0; tmp[13] = 0; tmp[14] = 0; tmp[15] = 0;
        uint4 lo = { (unsigned)tmp[0] | ((unsigned)tmp[1] << 16), (unsigned)tmp[2] | ((unsigned)tmp[3] << 16),
                     (unsigned)tmp[4] | ((unsigned)tmp[5] << 16), (unsigned)tmp[6] | ((unsigned)tmp[7] << 16) };
        uint4 hi = { (unsigned)tmp[8] | ((unsigned)tmp[9] << 16), (unsigned)tmp[10] | ((unsigned)tmp[11] << 16),
                     (unsigned)tmp[12] | ((unsigned)tmp[13] << 16), (unsigned)tmp[14] | ((unsigned)tmp[15] << 16) };
        const size_t o1 = (((size_t)(n >> 1) * 128 + hh) * 2 + (n & 1)) * 16;
        *(uint4*)(W1t + o1) = lo;
        *(uint4*)(W1t + o1 + 8) = hi;
        if (hh < 64) {
            const unsigned short a = bfr(W2[(size_t)(hh * 2 + 0) * 2048 + n]);
            const unsigned short g = bfr(W2[(size_t)(hh * 2 + 1) * 2048 + n]);
            *(unsigned int*)(W2t + (((size_t)(n >> 1) * 64 + hh) * 2 + (n & 1)) * 2) =
                (unsigned)a | ((unsigned)g << 16);
        }
    } else if (bid < 4201) {
        // s6a
        __shared__ float Ws[8 * 512];
        __shared__ float bsl[512];
        __shared__ float part[8 * 264];
        __shared__ float partq[8 * 9];
        const int lb = bid - 4137;
        const int h = lb >> 3, dq8 = lb & 7;
        const int r0 = h * 64 + dq8 * 8;
#pragma unroll
        for (int i = 0; i < 4; ++i) {
            const int flat = tid + 256 * i;
            const int row = flat >> 7, cq = flat & 127;
            *(float4*)&Ws[row * 512 + cq * 4] =
                *(const float4*)(Win + (size_t)(r0 + row) * 512 + cq * 4);
        }
        if (tid < 128) *(float4*)&bsl[tid * 4] = *(const float4*)(bq + tid * 4);
        __syncthreads();
        const int kq = tid >> 5, j = tid & 31;
        const int k0 = kq * 64;
        float acc[8] = {0, 0, 0, 0, 0, 0, 0, 0};
        for (int k = 0; k < 64; ++k) {
            const float wqv = Wq[(k0 + k) * 32 + j];
#pragma unroll
            for (int dd = 0; dd < 8; ++dd)
                acc[dd] = fmaf(Ws[dd * 512 + k0 + k], wqv, acc[dd]);
        }
#pragma unroll
        for (int dd = 0; dd < 8; ++dd) part[kq * 264 + dd * 33 + j] = acc[dd];
        if (j < 8) {
            float s = 0.0f;
            for (int k = 0; k < 64; ++k) s = fmaf(Ws[j * 512 + k0 + k], bsl[k0 + k], s);
            partq[kq * 9 + j] = s;
        }
        __syncthreads();
        {
            const int d = tid >> 5, jj = tid & 31;
            float s = 0.0f;
#pragma unroll
            for (int q = 0; q < 8; ++q) s += part[q * 264 + d * 33 + jj];
            Mb[((size_t)(r0 + d)) * 32 + jj] = bfr(s);
        }
        if (tid < 8) {
            float s = b_in[r0 + tid];
#pragma unroll
            for (int q = 0; q < 8; ++q) s += partq[q * 9 + tid];
            qc0[r0 + tid] = s;
        }
    } else {
        // Winb[r][k] = bf16(Win[512+r][k]), r<1024, coalesced
        const int lb = bid - 4201;
#pragma unroll
        for (int it = 0; it < 4; ++it) {
            const int flat = (lb * 4 + it) * 256 + tid;   // unit = 8 elems
            const int row = flat >> 6, u8 = flat & 63;
            const float4 v0 = *(const float4*)(Win + (size_t)(512 + row) * 512 + u8 * 8);
            const float4 v1 = *(const float4*)(Win + (size_t)(512 + row) * 512 + u8 * 8 + 4);
            uint4 o = { bf2(v0.x, v0.y), bf2(v0.z, v0.w), bf2(v1.x, v1.y), bf2(v1.z, v1.w) };
            *(uint4*)(Winb + (size_t)row * 512 + u8 * 8) = o;
        }
    }
}

// ---------------------------------------------------------------------------
// S2: Wallt[k<512] = bf16( Wsyn[:, :512] @ Wattn_o )
// ---------------------------------------------------------------------------
__global__ __launch_bounds__(256) void s2_wfused(
    const float* __restrict__ Wsyn, const float* __restrict__ Wao,
    unsigned short* __restrict__ Wallt)
{
    __shared__ float As[16][68];
    __shared__ float Bs[16][68];
    const int tid = threadIdx.x;
    const int cb = blockIdx.x & 7;
    const int rb = blockIdx.x >> 3;
    const int r0 = rb * 64, c0 = cb * 64;
    const int ra = tid >> 2, kq = tid & 3;
    const int bk = tid >> 4, bq2 = tid & 15;
    const int tx = tid & 15, ty = tid >> 4;
    float acc[4][4];
#pragma unroll
    for (int i = 0; i < 4; ++i)
#pragma unroll
        for (int j = 0; j < 4; ++j) acc[i][j] = 0.0f;

    for (int kt = 0; kt < 512; kt += 16) {
        const float4 av = *(const float4*)(Wsyn + (size_t)(r0 + ra) * 2560 + kt + kq * 4);
        const float4 bv = *(const float4*)(Wao + (size_t)(kt + bk) * 512 + c0 + bq2 * 4);
        __syncthreads();
        As[kq*4+0][ra] = av.x; As[kq*4+1][ra] = av.y; As[kq*4+2][ra] = av.z; As[kq*4+3][ra] = av.w;
        *(float4*)&Bs[bk][bq2*4] = bv;
        __syncthreads();
#pragma unroll
        for (int kk = 0; kk < 16; ++kk) {
            const float4 a4 = *(const float4*)&As[kk][ty*4];
            const float4 b4 = *(const float4*)&Bs[kk][tx*4];
            const float a[4] = {a4.x, a4.y, a4.z, a4.w};
            const float b[4] = {b4.x, b4.y, b4.z, b4.w};
#pragma unroll
            for (int i = 0; i < 4; ++i)
#pragma unroll
                for (int j = 0; j < 4; ++j) acc[i][j] = fmaf(a[i], b[j], acc[i][j]);
        }
    }
#pragma unroll
    for (int i = 0; i < 4; ++i) {
        const int gr = r0 + ty*4 + i;
        uint2 o = { bf2(acc[i][0], acc[i][1]), bf2(acc[i][2], acc[i][3]) };
        *(uint2*)(Wallt + wallt_idx(gr, c0 + tx*4)) = o;
    }
}

// ---------------------------------------------------------------------------
// S1: MFMA bf16 GEMM: C(16384x1024) = gather(emb,tok) @ Winb^T -> khb/vhb
// B pre-converted to bf16 (no per-tile conversion); LDS-transposed epilogue
// ---------------------------------------------------------------------------
__global__ __launch_bounds__(256) void s1_kv_mfma(
    const int* __restrict__ tok, const float* __restrict__ emb,
    const unsigned short* __restrict__ Winb, const float* __restrict__ b_in,
    unsigned short* __restrict__ khb, unsigned short* __restrict__ vhb)
{
    __shared__ alignas(16) unsigned short SM[17408];
    unsigned short* Al = SM;
    unsigned short* Bl = SM + 8192;
    const int tid = threadIdx.x;
    const int cb = blockIdx.x >> 7;
    const int rb = blockIdx.x & 127;
    const int r0 = rb * 128, c0 = cb * 128;
    int tokrow[8];
#pragma unroll
    for (int j = 0; j < 8; ++j) tokrow[j] = tok[r0 + ((tid + 256 * j) >> 4)];

    const int wid = tid >> 6, lane = tid & 63;
    const int wm = (wid >> 1) * 64, wn = (wid & 1) * 64;
    const int fr = lane & 15;
    const int fkb = (lane >> 4) * 16;
    f32x4 acc[4][4];
#pragma unroll
    for (int i = 0; i < 4; ++i)
#pragma unroll
        for (int j = 0; j < 4; ++j)
#pragma unroll
            for (int e = 0; e < 4; ++e) acc[i][j][e] = 0.0f;

    for (int kt = 0; kt < 512; kt += 64) {
        float4 av[8];
        uint4 bv4[4];
#pragma unroll
        for (int j = 0; j < 8; ++j) {
            const int flat = tid + 256 * j;
            const int row = flat >> 4, kq4 = flat & 15;
            av[j] = *(const float4*)(emb + (size_t)tokrow[j] * 512 + kt + kq4 * 4);
        }
#pragma unroll
        for (int j = 0; j < 4; ++j) {
            const int flat = tid + 256 * j;
            const int row = flat >> 3, kq8 = flat & 7;
            bv4[j] = *(const uint4*)(Winb + (size_t)(c0 + row) * 512 + kt + kq8 * 8);
        }
        __syncthreads();
#pragma unroll
        for (int j = 0; j < 8; ++j) {
            const int flat = tid + 256 * j;
            const int row = flat >> 4, kq4 = flat & 15;
            const int boff = row * 128 + kq4 * 8;
            uint2 pa = { bf2(av[j].x, av[j].y), bf2(av[j].z, av[j].w) };
            *(uint2*)((char*)Al + SWZ(boff)) = pa;
        }
#pragma unroll
        for (int j = 0; j < 4; ++j) {
            const int flat = tid + 256 * j;
            const int row = flat >> 3, kq8 = flat & 7;
            const int boff = row * 128 + kq8 * 16;
            *(uint4*)((char*)Bl + SWZ(boff)) = bv4[j];
        }
        __syncthreads();
#pragma unroll
        for (int ks = 0; ks < 2; ++ks) {
            short8v af[4], bfv[4];
#pragma unroll
            for (int i = 0; i < 4; ++i)
                af[i] = *(const short8v*)((const char*)Al + SWZ((wm + i * 16 + fr) * 128 + ks * 64 + fkb));
#pragma unroll
            for (int j = 0; j < 4; ++j)
                bfv[j] = *(const short8v*)((const char*)Bl + SWZ((wn + j * 16 + fr) * 128 + ks * 64 + fkb));
#pragma unroll
            for (int i = 0; i < 4; ++i)
#pragma unroll
                for (int j = 0; j < 4; ++j)
                    acc[i][j] = __builtin_amdgcn_mfma_f32_16x16x32_bf16(af[i], bfv[j], acc[i][j], 0, 0, 0);
        }
    }
    __syncthreads();
#pragma unroll
    for (int j = 0; j < 4; ++j) {
        const int n = wn + j * 16 + fr;
        const float bias = b_in[512 + c0 + n];
#pragma unroll
        for (int i = 0; i < 4; ++i) {
            const int rbase = wm + i * 16 + (lane >> 4) * 4;
#pragma unroll
            for (int rr = 0; rr < 4; ++rr)
                SM[(rbase + rr) * 136 + n] = bfr(acc[i][j][rr] + bias);
        }
    }
    __syncthreads();
    unsigned short* outbase = (c0 < 512) ? khb : vhb;
    const int ccol = (c0 < 512) ? c0 : (c0 - 512);
    {
        const int orow = tid >> 1, oh = tid & 1;
        unsigned short* gdst = outbase + (size_t)(r0 + orow) * 512 + ccol + oh * 64;
        const unsigned short* lsrc = SM + orow * 136 + oh * 64;
#pragma unroll
        for (int q = 0; q < 8; ++q)
            *(uint4*)(gdst + q * 8) = *(const uint4*)(lsrc + q * 8);
    }
}

// ---------------------------------------------------------------------------
// SETUP2 (after s1): [0,32) s6w: WMt + kmc; [32,544) s6c: khc
// ---------------------------------------------------------------------------
__global__ __launch_bounds__(256) void setup2(
    const float* __restrict__ Win, const float* __restrict__ b_in,
    const unsigned short* __restrict__ Mb, const float* __restrict__ qc0,
    const unsigned short* __restrict__ khb,
    unsigned short* __restrict__ WMt, float* __restrict__ kmc,
    float* __restrict__ khc)
{
    const int tid = threadIdx.x;
    const int bid = blockIdx.x;
    if (bid < 32) {
        __shared__ float Ws[64 * 128];
        __shared__ float Mf[64 * 33];
        __shared__ float bp[64];
        const int h = bid >> 2, ct = bid & 3;
#pragma unroll
        for (int i = 0; i < 8; ++i) {
            const int flat4 = tid + 256 * i;
            const int d = flat4 >> 5, cl4 = flat4 & 31;
            *(float4*)&Ws[d * 128 + cl4 * 4] =
                *(const float4*)(Win + (size_t)(512 + h * 64 + d) * 512 + ct * 128 + cl4 * 4);
        }
#pragma unroll
        for (int i = 0; i < 8; ++i) {
            const int flat = tid + 256 * i;
            const int d = flat >> 5, j2 = flat & 31;
            Mf[d * 33 + j2] = bff(Mb[(size_t)(h * 64 + d) * 32 + j2]);
        }
        if (tid < 64) bp[tid] = b_in[512 + h * 64 + tid];
        __syncthreads();
        const int j = tid & 31, clg = tid >> 5;
        float accw[16];
#pragma unroll
        for (int i = 0; i < 16; ++i) accw[i] = 0.0f;
        for (int d = 0; d < 64; ++d) {
            const float mf = Mf[d * 33 + j];
            const float* wr = &Ws[d * 128 + clg * 16];
#pragma unroll
            for (int i = 0; i < 16; ++i) accw[i] = fmaf(wr[i], mf, accw[i]);
        }
#pragma unroll
        for (int i = 0; i < 16; ++i)
            WMt[(size_t)(h * 32 + j) * 512 + ct * 128 + clg * 16 + i] = bfr(accw[i]);
        if (ct == 0 && clg == 0) {
            float s = 0.0f;
            for (int d = 0; d < 64; ++d) s = fmaf(bp[d], Mf[d * 33 + j], s);
            kmc[h * 32 + j] = s;
        }
    } else {
        __shared__ float qls[512];
        const int sb = bid - 32;
        qls[tid] = qc0[tid];
        qls[tid + 256] = qc0[tid + 256];
        __syncthreads();
        const int h = tid & 7, rl = tid >> 3;
        const int r = sb * 32 + rl;
        const unsigned short* kr = khb + (size_t)r * 512 + h * 64;
        const float* q8 = &qls[h * 64];
        float kc = 0.0f;
#pragma unroll
        for (int i = 0; i < 8; ++i) {
            const uint4 kv = *(const uint4*)(kr + i * 8);
            kc = fmaf(BLO(kv.x), q8[i*8+0], kc); kc = fmaf(BHI(kv.x), q8[i*8+1], kc);
            kc = fmaf(BLO(kv.y), q8[i*8+2], kc); kc = fmaf(BHI(kv.y), q8[i*8+3], kc);
            kc = fmaf(BLO(kv.z), q8[i*8+4], kc); kc = fmaf(BHI(kv.z), q8[i*8+5], kc);
            kc = fmaf(BLO(kv.w), q8[i*8+6], kc); kc = fmaf(BHI(kv.w), q8[i*8+7], kc);
        }
        khc[((size_t)(r >> 9) * 8 + h) * 512 + (r & 511)] = kc;
    }
}

// ---------------------------------------------------------------------------
// S7: MFMA bf16 GEMM: khM(16384 x 256) = gather(emb,tok) @ WMt^T + kmc
// ---------------------------------------------------------------------------
__global__ __launch_bounds__(256) void s7_khm_mfma(
    const int* __restrict__ tok, const float* __restrict__ emb,
    const unsigned short* __restrict__ WMt, const float* __restrict__ kmc,
    unsigned short* __restrict__ khM)
{
    __shared__ alignas(16) unsigned short Al[128 * 64];
    __shared__ alignas(16) unsigned short Bl[128 * 64];
    const int tid = threadIdx.x;
    const int cb = blockIdx.x >> 7;
    const int rb = blockIdx.x & 127;
    const int r0 = rb * 128, c0 = cb * 128;
    int tokrow[8];
#pragma unroll
    for (int j = 0; j < 8; ++j) tokrow[j] = tok[r0 + ((tid + 256 * j) >> 4)];

    const int wid = tid >> 6, lane = tid & 63;
    const int wm = (wid >> 1) * 64, wn = (wid & 1) * 64;
    const int fr = lane & 15;
    const int fkb = (lane >> 4) * 16;
    f32x4 acc[4][4];
#pragma unroll
    for (int i = 0; i < 4; ++i)
#pragma unroll
        for (int j = 0; j < 4; ++j)
#pragma unroll
            for (int e = 0; e < 4; ++e) acc[i][j][e] = 0.0f;

    for (int kt = 0; kt < 512; kt += 64) {
        float4 av[8];
        uint4 bv4[4];
#pragma unroll
        for (int j = 0; j < 8; ++j) {
            const int flat = tid + 256 * j;
            const int row = flat >> 4, kq4 = flat & 15;
            av[j] = *(const float4*)(emb + (size_t)tokrow[j] * 512 + kt + kq4 * 4);
        }
#pragma unroll
        for (int j = 0; j < 4; ++j) {
            const int flat = tid + 256 * j;
            const int row = flat >> 3, kq8 = flat & 7;
            bv4[j] = *(const uint4*)(WMt + (size_t)(c0 + row) * 512 + kt + kq8 * 8);
        }
        __syncthreads();
#pragma unroll
        for (int j = 0; j < 8; ++j) {
            const int flat = tid + 256 * j;
            const int row = flat >> 4, kq4 = flat & 15;
            const int boff = row * 128 + kq4 * 8;
            uint2 pa = { bf2(av[j].x, av[j].y), bf2(av[j].z, av[j].w) };
            *(uint2*)((char*)Al + SWZ(boff)) = pa;
        }
#pragma unroll
        for (int j = 0; j < 4; ++j) {
            const int flat = tid + 256 * j;
            const int row = flat >> 3, kq8 = flat & 7;
            const int boff = row * 128 + kq8 * 16;
            *(uint4*)((char*)Bl + SWZ(boff)) = bv4[j];
        }
        __syncthreads();
#pragma unroll
        for (int ks = 0; ks < 2; ++ks) {
            short8v af[4], bfv[4];
#pragma unroll
            for (int i = 0; i < 4; ++i)
                af[i] = *(const short8v*)((const char*)Al + SWZ((wm + i * 16 + fr) * 128 + ks * 64 + fkb));
#pragma unroll
            for (int j = 0; j < 4; ++j)
                bfv[j] = *(const short8v*)((const char*)Bl + SWZ((wn + j * 16 + fr) * 128 + ks * 64 + fkb));
#pragma unroll
            for (int i = 0; i < 4; ++i)
#pragma unroll
                for (int j = 0; j < 4; ++j)
                    acc[i][j] = __builtin_amdgcn_mfma_f32_16x16x32_bf16(af[i], bfv[j], acc[i][j], 0, 0, 0);
        }
    }
#pragma unroll
    for (int j = 0; j < 4; ++j) {
        const int n = wn + j * 16 + fr;
        const int gc = c0 + n;
        const int h = gc >> 5, jj = gc & 31;
        const float kadd = kmc[gc];
#pragma unroll
        for (int i = 0; i < 4; ++i) {
            const int rbase = wm + i * 16 + (lane >> 4) * 4;
#pragma unroll
            for (int rr = 0; rr < 4; ++rr) {
                const int gr = r0 + rbase + rr;
                khM[(((size_t)(gr >> 9) * 8 + h) * 512 + (gr & 511)) * 32 + jj] =
                    bfr(acc[i][j][rr] + kadd);
            }
        }
    }
}

// ---------------------------------------------------------------------------
// K1: per (b,h), 512 thr: EMA; score = 0.125*(khM.sync + khc); shfl softmax;
// PV from preloaded vh regs -> Abt bf16
// ---------------------------------------------------------------------------
__global__ __launch_bounds__(512) void k1_attn(
    const float* __restrict__ act, const float* __restrict__ decay_a,
    const float* __restrict__ decay_o, const int* __restrict__ ial,
    const int* __restrict__ iar, const int* __restrict__ iol,
    const int* __restrict__ ior,
    const unsigned short* __restrict__ khM, const float* __restrict__ khc,
    const unsigned short* __restrict__ vhb, float* __restrict__ aaB,
    float* __restrict__ baB, float* __restrict__ aoB, float* __restrict__ boB,
    unsigned short* __restrict__ Abt, float* __restrict__ stats, const int u)
{
    __shared__ float sync_lds[32];
    __shared__ float sc[512];
    __shared__ float red[16];
    __shared__ float pvred[512];
    const int tid = threadIdx.x;
    const int b = blockIdx.x >> 3, h = blockIdx.x & 7;

    const size_t mb = (((size_t)b * 8 + h) * 512 + tid) * 32;
    const uint4 km0 = *(const uint4*)(khM + mb);
    const uint4 km1 = *(const uint4*)(khM + mb + 8);
    const uint4 km2 = *(const uint4*)(khM + mb + 16);
    const uint4 km3 = *(const uint4*)(khM + mb + 24);
    const float kc = khc[((size_t)b * 8 + h) * 512 + tid];
    const int l = tid & 63, w = tid >> 6;
    const unsigned short* vb = vhb + ((size_t)(b * 512 + w * 64)) * 512 + h * 64 + l;
    unsigned short vraw[64];
#pragma unroll
    for (int si = 0; si < 64; ++si) vraw[si] = vb[(size_t)si * 512];

    if (tid < 32) {
        const int j = tid;
        const float ra = decf(decay_a[j]);
        const float pa = act[b*2048 + ial[j]] * act[b*2048 + iar[j]];
        const float aa = fmaf(ra, aaB[(u & 1)*1024 + b*32 + j], pa);
        const float ban = fmaf(ra, baB[(u & 1)*1024 + b*32 + j], 1.0f);
        if (h == 0) { aaB[((u+1)&1)*1024 + b*32 + j] = aa; baB[((u+1)&1)*1024 + b*32 + j] = ban; }
        sync_lds[j] = aa * rsqrtf(ban);
    } else if (tid >= 64 && tid < 128) {
        if (u > 0) {
            const int j = tid - 64;
            const float ro = decf(decay_o[j]);
            const float po = act[b*2048 + iol[j]] * act[b*2048 + ior[j]];
            const float ao = fmaf(ro, aoB[((u-1)&1)*2048 + b*64 + j], po);
            const float bo = fmaf(ro, boB[((u-1)&1)*2048 + b*64 + j], 1.0f);
            if (h == 0) { aoB[(u&1)*2048 + b*64 + j] = ao; boB[(u&1)*2048 + b*64 + j] = bo; }
        }
    } else if (tid >= 128 && tid < 192) {
        if (u > 0 && blockIdx.x == 0) stats[tid - 128] = 0.0f;
    }
    __syncthreads();
    float sv = kc;
    {
        const float* sy = sync_lds;
        sv = fmaf(BLO(km0.x), sy[0], sv);  sv = fmaf(BHI(km0.x), sy[1], sv);
        sv = fmaf(BLO(km0.y), sy[2], sv);  sv = fmaf(BHI(km0.y), sy[3], sv);
        sv = fmaf(BLO(km0.z), sy[4], sv);  sv = fmaf(BHI(km0.z), sy[5], sv);
        sv = fmaf(BLO(km0.w), sy[6], sv);  sv = fmaf(BHI(km0.w), sy[7], sv);
        sv = fmaf(BLO(km1.x), sy[8], sv);  sv = fmaf(BHI(km1.x), sy[9], sv);
        sv = fmaf(BLO(km1.y), sy[10], sv); sv = fmaf(BHI(km1.y), sy[11], sv);
        sv = fmaf(BLO(km1.z), sy[12], sv); sv = fmaf(BHI(km1.z), sy[13], sv);
        sv = fmaf(BLO(km1.w), sy[14], sv); sv = fmaf(BHI(km1.w), sy[15], sv);
        sv = fmaf(BLO(km2.x), sy[16], sv); sv = fmaf(BHI(km2.x), sy[17], sv);
        sv = fmaf(BLO(km2.y), sy[18], sv); sv = fmaf(BHI(km2.y), sy[19], sv);
        sv = fmaf(BLO(km2.z), sy[20], sv); sv = fmaf(BHI(km2.z), sy[21], sv);
        sv = fmaf(BLO(km2.w), sy[22], sv); sv = fmaf(BHI(km2.w), sy[23], sv);
        sv = fmaf(BLO(km3.x), sy[24], sv); sv = fmaf(BHI(km3.x), sy[25], sv);
        sv = fmaf(BLO(km3.y), sy[26], sv); sv = fmaf(BHI(km3.y), sy[27], sv);
        sv = fmaf(BLO(km3.z), sy[28], sv); sv = fmaf(BHI(km3.z), sy[29], sv);
        sv = fmaf(BLO(km3.w), sy[30], sv); sv = fmaf(BHI(km3.w), sy[31], sv);
    }
    const float v = sv * 0.125f;
    const int wid = tid >> 6;
    float m = v;
#pragma unroll
    for (int off = 32; off > 0; off >>= 1) m = fmaxf(m, __shfl_xor(m, off));
    if ((tid & 63) == 0) red[wid] = m;
    __syncthreads();
    float mx = red[0];
#pragma unroll
    for (int j = 1; j < 8; ++j) mx = fmaxf(mx, red[j]);
    const float e = __expf(v - mx);
    sc[tid] = e;
    float s = e;
#pragma unroll
    for (int off = 32; off > 0; off >>= 1) s += __shfl_xor(s, off);
    if ((tid & 63) == 0) red[8 + wid] = s;
    __syncthreads();
    float tot = red[8];
#pragma unroll
    for (int j = 1; j < 8; ++j) tot += red[8 + j];
    const float inv = 1.0f / tot;
    {
        float a3 = 0.0f;
#pragma unroll
        for (int si = 0; si < 64; ++si)
            a3 = fmaf(sc[w*64 + si], bff(vraw[si]), a3);
        pvred[w*64 + l] = a3;
    }
    __syncthreads();
    if (tid < 64) {
        float a = 0.0f;
#pragma unroll
        for (int j = 0; j < 8; ++j) a += pvred[j*64 + tid];
        Abt[abt_idx(b, h*64 + tid)] = bfr(a * inv);
    }
}

// ---------------------------------------------------------------------------
// K2b: synapse via MFMA, 1024 thr / 16-way K-split -> GLU -> sg; LN stats
// ---------------------------------------------------------------------------
__global__ __launch_bounds__(1024) void k2b_syn(
    const unsigned short* __restrict__ Abt, const unsigned short* __restrict__ Wallt,
    const float* __restrict__ bsyn2, float* __restrict__ sg, float* __restrict__ stats)
{
    __shared__ float part[16 * 512];   // 32 KB
    const int tid = threadIdx.x;
    const int c0 = blockIdx.x * 8;
    const int w = tid >> 6, lane = tid & 63, fr = lane & 15, kq = lane >> 4;
    const int kb0 = w * 20 + kq;
    const unsigned short* wrow = Wallt + (((size_t)blockIdx.x * 320 + kb0) * 16 + fr) * 8;
    const unsigned short* ar0 = Abt + (((size_t)kb0) * 32 + fr) * 8;
    const unsigned short* ar1 = ar0 + 128;
    f32x4 acc0 = {0.f,0.f,0.f,0.f}, acc1 = {0.f,0.f,0.f,0.f};
#pragma unroll
    for (int kk = 0; kk < 5; ++kk) {
        const short8v bfrag = *(const short8v*)(wrow + kk*512);
        const short8v a0f = *(const short8v*)(ar0 + kk*1024);
        const short8v a1f = *(const short8v*)(ar1 + kk*1024);
        acc0 = __builtin_amdgcn_mfma_f32_16x16x32_bf16(a0f, bfrag, acc0, 0, 0, 0);
        acc1 = __builtin_amdgcn_mfma_f32_16x16x32_bf16(a1f, bfrag, acc1, 0, 0, 0);
    }
#pragma unroll
    for (int r = 0; r < 4; ++r) {
        part[w*512 + (kq*4 + r)*16 + fr] = acc0[r];
        part[w*512 + 256 + (kq*4 + r)*16 + fr] = acc1[r];
    }
    __syncthreads();
    if (tid < 512) {
        float rs = 0.0f;
#pragma unroll
        for (int w2 = 0; w2 < 16; ++w2) rs += part[w2*512 + tid];
        const float other = __shfl_xor(rs, 8);
        const int coli = tid & 15;
        const int m = ((tid >> 8) << 4) | ((tid >> 4) & 15);
        float gval = 0.0f;
        if (coli < 8) {
            const int c = c0 + coli;
            const float va = rs + bsyn2[c];
            const float vg = other + bsyn2[2048 + c];
            gval = va * sigf(vg);
            sg[m*2048 + c] = gval;
        }
        float s1 = gval, s2v = gval*gval;
        s1 += __shfl_xor(s1, 1); s2v += __shfl_xor(s2v, 1);
        s1 += __shfl_xor(s1, 2); s2v += __shfl_xor(s2v, 2);
        s1 += __shfl_xor(s1, 4); s2v += __shfl_xor(s2v, 4);
        if (coli == 0) {
            atomicAdd(&stats[m*2],     s1);
            atomicAdd(&stats[m*2 + 1], s2v);
        }
    }
}

// ---------------------------------------------------------------------------
// K3: LN + trace + per-neuron NLM -> act (+Abt). grid 1024 (2 neurons), 256 thr
// ---------------------------------------------------------------------------
__global__ __launch_bounds__(256) void k3_nlm(
    const float* __restrict__ sg, const float* __restrict__ stats,
    const float* __restrict__ ln_g, const float* __restrict__ ln_b,
    const unsigned short* __restrict__ W1t, const unsigned short* __restrict__ W2t,
    const float* __restrict__ b2,
    float* __restrict__ trace, float* __restrict__ act,
    unsigned short* __restrict__ Abt, const int u)
{
    __shared__ float tr[64 * 12];
    __shared__ float pk[64 * 133];
    const int tid = threadIdx.x;
    const int n0 = blockIdx.x * 2;
    if (tid < 64) {
        const int bb = tid >> 1, nl0 = tid & 1;
        const int n = n0 + nl0;
        float* trow = &tr[tid * 12];
#pragma unroll
        for (int m = 0; m < 9; ++m) {
            const int slot = (u + 1 + m) % 10;
            trow[m] = trace[(bb*10 + slot)*2048 + n];
        }
        const float mean = stats[bb*2] * (1.0f/2048.0f);
        const float var  = stats[bb*2+1] * (1.0f/2048.0f) - mean*mean;
        const float rstd = rsqrtf(var + 1e-5f);
        const float v9 = (sg[bb*2048 + n] - mean) * rstd * ln_g[n] + ln_b[n];
        trow[9] = v9;
        trace[(bb*10 + (u % 10))*2048 + n] = v9;
    }
    const int nl = tid & 1, hg = (tid >> 1) & 63, bh = tid >> 7;
    float w1a[10], w1g[10], b1a, b1g, w2v0, w2v1;
    {
        const unsigned short* pa = W1t + (((size_t)blockIdx.x*128 + hg)*2 + nl)*16;
        const uint4 qa = *(const uint4*)pa;
        const uint4 qb = *(const uint4*)(pa + 8);
        w1a[0] = BLO(qa.x); w1a[1] = BHI(qa.x); w1a[2] = BLO(qa.y); w1a[3] = BHI(qa.y);
        w1a[4] = BLO(qa.z); w1a[5] = BHI(qa.z); w1a[6] = BLO(qa.w); w1a[7] = BHI(qa.w);
        w1a[8] = BLO(qb.x); w1a[9] = BHI(qb.x); b1a = BLO(qb.y);
        const unsigned short* pg = W1t + (((size_t)blockIdx.x*128 + 64 + hg)*2 + nl)*16;
        const uint4 ra = *(const uint4*)pg;
        const uint4 rb = *(const uint4*)(pg + 8);
        w1g[0] = BLO(ra.x); w1g[1] = BHI(ra.x); w1g[2] = BLO(ra.y); w1g[3] = BHI(ra.y);
        w1g[4] = BLO(ra.z); w1g[5] = BHI(ra.z); w1g[6] = BLO(ra.w); w1g[7] = BHI(ra.w);
        w1g[8] = BLO(rb.x); w1g[9] = BHI(rb.x); b1g = BLO(rb.y);
        const unsigned int q2 = *(const unsigned int*)(W2t + (((size_t)blockIdx.x*64 + hg)*2 + nl)*2);
        w2v0 = BLO(q2); w2v1 = BHI(q2);
    }
    __syncthreads();
#pragma unroll
    for (int bi = 0; bi < 16; ++bi) {
        const int bb = bh * 16 + bi;
        const float* trow = &tr[(bb*2 + nl)*12];
        const float4 t0 = *(const float4*)trow;
        const float4 t1 = *(const float4*)(trow + 4);
        const float2 t2 = *(const float2*)(trow + 8);
        const float t[10] = {t0.x,t0.y,t0.z,t0.w,t1.x,t1.y,t1.z,t1.w,t2.x,t2.y};
        float ha = b1a, hgv = b1g;
#pragma unroll
        for (int mm = 0; mm < 10; ++mm) {
            ha  = fmaf(t[mm], w1a[mm], ha);
            hgv = fmaf(t[mm], w1g[mm], hgv);
        }
        const float g0 = ha * sigf(hgv);
        pk[hg*133 + bb*4 + nl*2 + 0] = g0 * w2v0;
        pk[hg*133 + bb*4 + nl*2 + 1] = g0 * w2v1;
    }
    __syncthreads();
    if (tid < 128) {
        const int obb = tid >> 2, onl = (tid >> 1) & 1, oo = tid & 1;
        float rs = 0.0f;
#pragma unroll 8
        for (int q = 0; q < 64; ++q) rs += pk[q*133 + tid];
        rs += b2[(n0 + onl)*2 + oo];
        const float h2o = __shfl_xor(rs, 1);
        if (oo == 0) {
            const float actv = rs * sigf(h2o);
            act[obb*2048 + n0 + onl] = actv;
            Abt[abt_idx(obb, 512 + n0 + onl)] = bfr(actv);
        }
    }
}

// ---------------------------------------------------------------------------
// K4: final o-update, sync_o, ratings, cert
// ---------------------------------------------------------------------------
__global__ __launch_bounds__(256) void k4_final(
    const float* __restrict__ aoB, const float* __restrict__ boB,
    const float* __restrict__ act, const float* __restrict__ decay_o,
    const int* __restrict__ iol, const int* __restrict__ ior,
    const float* __restrict__ Wout, const float* __restrict__ bout,
    float* __restrict__ out)
{
    __shared__ float sl[2048];
    const int tid = threadIdx.x;
    for (int idx = tid; idx < 2048; idx += 256) {
        const int b = idx >> 6, j = idx & 63;
        const float ro = decf(decay_o[j]);
        const float po = act[b*2048 + iol[j]] * act[b*2048 + ior[j]];
        const float ao = fmaf(ro, aoB[2048 + b*64 + j], po);
        const float bo = fmaf(ro, boB[2048 + b*64 + j], 1.0f);
        const float sv = ao * rsqrtf(bo);
        sl[idx] = sv;
        out[96 + idx] = sv;
    }
    __syncthreads();
    if (tid < 32) {
        float p = bout[0];
        for (int j = 0; j < 64; ++j) p = fmaf(sl[tid*64 + j], Wout[j], p);
        out[tid] = sigf(p);
    } else if (tid < 96) {
        out[32 + (tid - 32)] = ((tid - 32) & 1) ? 1.0f : 0.0f;
    }
}

// ---------------------------------------------------------------------------
extern "C" void kernel_launch(void* const* d_in, const int* in_sizes, int n_in,
                              void* d_out, int out_size, void* d_ws, size_t ws_size,
                              hipStream_t stream)
{
    (void)in_sizes; (void)n_in; (void)out_size;
    const int*   tok   = (const int*)  d_in[0];
    const float* emb   = (const float*)d_in[1];
    const float* st_tr = (const float*)d_in[2];
    const float* st_ac = (const float*)d_in[3];
    const float* dec_a = (const float*)d_in[4];
    const float* dec_o = (const float*)d_in[5];
    const int*   ial   = (const int*)  d_in[6];
    const int*   iar   = (const int*)  d_in[7];
    const int*   iol   = (const int*)  d_in[8];
    const int*   ior   = (const int*)  d_in[9];
    const float* Wq    = (const float*)d_in[10];
    const float* bq    = (const float*)d_in[11];
    const float* Win   = (const float*)d_in[12];
    const float* b_in  = (const float*)d_in[13];
    const float* Wao   = (const float*)d_in[14];
    const float* bao   = (const float*)d_in[15];
    const float* Wsyn  = (const float*)d_in[16];
    const float* bsyn  = (const float*)d_in[17];
    const float* ln_g  = (const float*)d_in[18];
    const float* ln_b  = (const float*)d_in[19];
    const float* W1    = (const float*)d_in[20];
    const float* b1    = (const float*)d_in[21];
    const float* W2    = (const float*)d_in[22];
    const float* b2    = (const float*)d_in[23];
    const float* Wout  = (const float*)d_in[24];
    const float* bout  = (const float*)d_in[25];
    float* out = (float*)d_out;
    char* wsb = (char*)d_ws;
    if (ws_size < (size_t)77073664) return;
    unsigned short* khb   = (unsigned short*)(wsb + 0);          // 16 MB
    unsigned short* vhb   = (unsigned short*)(wsb + 16777216);   // 16 MB
    unsigned short* Wallt = (unsigned short*)(wsb + 33554432);   // 20 MB
    unsigned short* W1t   = (unsigned short*)(wsb + 54525952);   // 8 MB
    unsigned short* W2t   = (unsigned short*)(wsb + 62914560);   // 512 KB
    unsigned short* khM   = (unsigned short*)(wsb + 63438848);   // 8 MB
    float* khc  = (float*)(wsb + 71827456);                      // 512 KB
    unsigned short* Mb    = (unsigned short*)(wsb + 72351744);   // 32 KB
    float* qc0  = (float*)(wsb + 72384512);                      // 2 KB
    float* trace = (float*)(wsb + 72386560);                     // 2.5 MB
    float* actb  = (float*)(wsb + 75008000);                     // 256 KB
    float* sg    = (float*)(wsb + 75270144);                     // 256 KB
    unsigned short* Abt = (unsigned short*)(wsb + 75532288);     // 160 KB
    float* aaB   = (float*)(wsb + 75696128);
    float* baB   = (float*)(wsb + 75704320);
    float* aoB   = (float*)(wsb + 75712512);
    float* boB   = (float*)(wsb + 75728896);
    float* bs2   = (float*)(wsb + 75745280);
    float* stats = (float*)(wsb + 75761664);
    unsigned short* WMt = (unsigned short*)(wsb + 75761920);     // 256 KB
    float* kmc  = (float*)(wsb + 76024064);                      // 1 KB
    unsigned short* Winb = (unsigned short*)(wsb + 76025088);    // 1 MB (1024x512 bf16)

    setup1<<<dim3(4265), dim3(256), 0, stream>>>(
        st_tr, st_ac, iol, ior, trace, actb, Abt, aaB, baB, aoB, boB, stats,
        Wsyn, Wallt, bao, bsyn, bs2, W1, b1, W2, W1t, W2t,
        Win, b_in, Wq, bq, Mb, qc0, Winb);
    s2_wfused<<<dim3(512), dim3(256), 0, stream>>>(Wsyn, Wao, Wallt);
    s1_kv_mfma<<<dim3(1024), dim3(256), 0, stream>>>(tok, emb, Winb, b_in, khb, vhb);
    setup2<<<dim3(544), dim3(256), 0, stream>>>(Win, b_in, Mb, qc0, khb, WMt, kmc, khc);
    s7_khm_mfma<<<dim3(256), dim3(256), 0, stream>>>(tok, emb, WMt, kmc, khM);
    for (int u = 0; u < 20; ++u) {
        k1_attn<<<dim3(256), dim3(512), 0, stream>>>(actb, dec_a, dec_o,
            ial, iar, iol, ior, khM, khc, vhb,
            aaB, baB, aoB, boB, Abt, stats, u);
        k2b_syn<<<dim3(256), dim3(1024), 0, stream>>>(Abt, Wallt, bs2, sg, stats);
        k3_nlm<<<dim3(1024), dim3(256), 0, stream>>>(sg, stats, ln_g, ln_b,
            W1t, W2t, b2, trace, actb, Abt, u);
    }
    k4_final<<<dim3(1), dim3(256), 0, stream>>>(aoB, boB, actb, dec_o,
        iol, ior, Wout, bout, out);
}

// Round 14
// 1136.277 us; speedup vs baseline: 1.0200x; 1.0200x over previous
//
#include <hip/hip_runtime.h>
#include <math.h>

// Sizes: B=32 S=512 V=32000 D_IN=512 D_MODEL=2048 HEADS=8 HD=64
//        N_OUT=64 N_ACT=32 M=10 MH=64 T=20

typedef __attribute__((ext_vector_type(8))) short short8v;
typedef __attribute__((ext_vector_type(4))) float f32x4;

__device__ __forceinline__ float sigf(float x) { return 1.0f / (1.0f + __expf(-x)); }
__device__ __forceinline__ float decf(float d) { return __expf(-fminf(fmaxf(d, 0.0f), 15.0f)); }
// single-instruction packed f32->bf16 (RNE), gfx950
__device__ __forceinline__ unsigned int bf2(float lo, float hi) {
    unsigned int r;
    asm("v_cvt_pk_bf16_f32 %0, %1, %2" : "=v"(r) : "v"(lo), "v"(hi));
    return r;
}
__device__ __forceinline__ unsigned short bfr(float x) {
    return (unsigned short)(bf2(x, 0.0f) & 0xFFFFu);
}
__device__ __forceinline__ float bff(unsigned short u) {
    return __uint_as_float(((unsigned int)u) << 16);
}
#define BLO(u) __uint_as_float((u) << 16)
#define BHI(u) __uint_as_float((u) & 0xFFFF0000u)
__device__ __forceinline__ int SWZ(int byteoff) {
    return byteoff ^ (((byteoff >> 7) & 7) << 4);
}
// Wallt layout: [cg 0..255][kb 0..319][fr 0..15][ke 0..7]
__device__ __forceinline__ size_t wallt_idx(int c, int k) {
    const int cg = (c & 2047) >> 3;
    const int fr = (c & 7) + ((c < 2048) ? 0 : 8);
    return (((size_t)cg * 320 + (k >> 3)) * 16 + fr) * 8 + (k & 7);
}
// Abt layout (MFMA-native A): [kb 0..319][b 0..31][ke 0..7]
__device__ __forceinline__ size_t abt_idx(int b, int k) {
    return (((size_t)(k >> 3)) * 32 + b) * 8 + (k & 7);
}

// ---------------------------------------------------------------------------
// SETUP1: merged cheap setup work, branch by blockIdx:
//   [0,2841)     k0 init; [2841,2857) s3 bsyn2; [2857,3113) s4 Wallt[k>=512]
//   (coalesced); [3113,4137) s5 NLM re-layout; [4137,4201) s6a M/qc0
// ---------------------------------------------------------------------------
__global__ __launch_bounds__(256) void setup1(
    const float* __restrict__ st_tr, const float* __restrict__ st_ac,
    const int* __restrict__ iol, const int* __restrict__ ior,
    float* __restrict__ trace, float* __restrict__ act,
    unsigned short* __restrict__ Abt,
    float* __restrict__ aaB, float* __restrict__ baB,
    float* __restrict__ aoB, float* __restrict__ boB, float* __restrict__ stats,
    const float* __restrict__ Wsyn, unsigned short* __restrict__ Wallt,
    const float* __restrict__ battn, const float* __restrict__ bsyn,
    float* __restrict__ bsyn2,
    const float* __restrict__ W1, const float* __restrict__ b1,
    const float* __restrict__ W2,
    unsigned short* __restrict__ W1t, unsigned short* __restrict__ W2t,
    const float* __restrict__ Win, const float* __restrict__ b_in,
    const float* __restrict__ Wq, const float* __restrict__ bq,
    unsigned short* __restrict__ Mb, float* __restrict__ qc0)
{
    const int tid = threadIdx.x;
    const int bid = blockIdx.x;
    if (bid < 2841) {
        const int i = bid * 256 + tid;
        if (i < 655360) {
            const int n = i & 2047;
            const int m = (i >> 11) % 10;
            trace[i] = st_tr[n * 10 + m];
        } else if (i < 720896) {
            const int j = i - 655360;
            const int n = j & 2047, b = j >> 11;
            const float v = st_ac[n];
            act[j] = v;
            Abt[abt_idx(b, 512 + n)] = bfr(v);
        } else if (i < 721920) {
            aaB[i - 720896] = 0.0f;
        } else if (i < 722944) {
            baB[i - 721920] = 0.0f;
        } else if (i < 724992) {
            const int j = i - 722944;
            const int k = j & 63;
            aoB[j] = st_ac[iol[k]] * st_ac[ior[k]];
        } else if (i < 727040) {
            boB[i - 724992] = 1.0f;
        } else if (i < 727104) {
            stats[i - 727040] = 0.0f;
        }
    } else if (bid < 2857) {
        const int c = (bid - 2841) * 256 + tid;
        float s = bsyn[c];
        const float4* wr = (const float4*)(Wsyn + (size_t)c * 2560);
#pragma unroll 4
        for (int k4 = 0; k4 < 128; ++k4) {
            const float4 w = wr[k4];
            const float4 bb = *(const float4*)(battn + k4*4);
            s += w.x*bb.x + w.y*bb.y + w.z*bb.z + w.w*bb.w;
        }
        bsyn2[c] = s;
    } else if (bid < 3113) {
        // s4: one cg per block; writes fully coalesced in Wallt order
        const int cg = bid - 2857;
#pragma unroll
        for (int it = 0; it < 16; ++it) {
            const int flat = it * 256 + tid;        // unit = 8 elements
            const int kb_rel = flat >> 4;           // 0..255  -> kb = 64 + kb_rel
            const int fr = flat & 15;
            const int row = cg * 8 + (fr & 7) + ((fr >= 8) ? 2048 : 0);
            const int k0 = 512 + kb_rel * 8;
            const float4 v0 = *(const float4*)(Wsyn + (size_t)row * 2560 + k0);
            const float4 v1 = *(const float4*)(Wsyn + (size_t)row * 2560 + k0 + 4);
            uint4 o = { bf2(v0.x, v0.y), bf2(v0.z, v0.w), bf2(v1.x, v1.y), bf2(v1.z, v1.w) };
            *(uint4*)(Wallt + (((size_t)cg * 320 + 64 + kb_rel) * 16 + fr) * 8) = o;
        }
    } else if (bid < 4137) {
        const int t = (bid - 3113) * 256 + tid;
        const int n = t & 2047, hh = t >> 11;
        unsigned short tmp[16];
#pragma unroll
        for (int m = 0; m < 10; ++m) tmp[m] = bfr(W1[(size_t)(m * 128 + hh) * 2048 + n]);
        tmp[10] = bfr(b1[n * 128 + hh]);
        tmp[11] = 0; tmp[12] = 0; tmp[13] = 0; tmp[14] = 0; tmp[15] = 0;
        uint4 lo = { (unsigned)tmp[0] | ((unsigned)tmp[1] << 16), (unsigned)tmp[2] | ((unsigned)tmp[3] << 16),
                     (unsigned)tmp[4] | ((unsigned)tmp[5] << 16), (unsigned)tmp[6] | ((unsigned)tmp[7] << 16) };
        uint4 hi = { (unsigned)tmp[8] | ((unsigned)tmp[9] << 16), (unsigned)tmp[10] | ((unsigned)tmp[11] << 16),
                     (unsigned)tmp[12] | ((unsigned)tmp[13] << 16), (unsigned)tmp[14] | ((unsigned)tmp[15] << 16) };
        const size_t o1 = (((size_t)(n >> 1) * 128 + hh) * 2 + (n & 1)) * 16;
        *(uint4*)(W1t + o1) = lo;
        *(uint4*)(W1t + o1 + 8) = hi;
        if (hh < 64) {
            const unsigned short a = bfr(W2[(size_t)(hh * 2 + 0) * 2048 + n]);
            const unsigned short g = bfr(W2[(size_t)(hh * 2 + 1) * 2048 + n]);
            *(unsigned int*)(W2t + (((size_t)(n >> 1) * 64 + hh) * 2 + (n & 1)) * 2) =
                (unsigned)a | ((unsigned)g << 16);
        }
    } else {
        // s6a
        __shared__ float Ws[8 * 512];
        __shared__ float bsl[512];
        __shared__ float part[8 * 264];
        __shared__ float partq[8 * 9];
        const int lb = bid - 4137;
        const int h = lb >> 3, dq8 = lb & 7;
        const int r0 = h * 64 + dq8 * 8;
#pragma unroll
        for (int i = 0; i < 4; ++i) {
            const int flat = tid + 256 * i;
            const int row = flat >> 7, cq = flat & 127;
            *(float4*)&Ws[row * 512 + cq * 4] =
                *(const float4*)(Win + (size_t)(r0 + row) * 512 + cq * 4);
        }
        if (tid < 128) *(float4*)&bsl[tid * 4] = *(const float4*)(bq + tid * 4);
        __syncthreads();
        const int kq = tid >> 5, j = tid & 31;
        const int k0 = kq * 64;
        float acc[8] = {0, 0, 0, 0, 0, 0, 0, 0};
        for (int k = 0; k < 64; ++k) {
            const float wqv = Wq[(k0 + k) * 32 + j];
#pragma unroll
            for (int dd = 0; dd < 8; ++dd)
                acc[dd] = fmaf(Ws[dd * 512 + k0 + k], wqv, acc[dd]);
        }
#pragma unroll
        for (int dd = 0; dd < 8; ++dd) part[kq * 264 + dd * 33 + j] = acc[dd];
        if (j < 8) {
            float s = 0.0f;
            for (int k = 0; k < 64; ++k) s = fmaf(Ws[j * 512 + k0 + k], bsl[k0 + k], s);
            partq[kq * 9 + j] = s;
        }
        __syncthreads();
        {
            const int d = tid >> 5, jj = tid & 31;
            float s = 0.0f;
#pragma unroll
            for (int q = 0; q < 8; ++q) s += part[q * 264 + d * 33 + jj];
            Mb[((size_t)(r0 + d)) * 32 + jj] = bfr(s);
        }
        if (tid < 8) {
            float s = b_in[r0 + tid];
#pragma unroll
            for (int q = 0; q < 8; ++q) s += partq[q * 9 + tid];
            qc0[r0 + tid] = s;
        }
    }
}

// ---------------------------------------------------------------------------
// S2: Wallt[k<512] = bf16( Wsyn[:, :512] @ Wattn_o )
// ---------------------------------------------------------------------------
__global__ __launch_bounds__(256) void s2_wfused(
    const float* __restrict__ Wsyn, const float* __restrict__ Wao,
    unsigned short* __restrict__ Wallt)
{
    __shared__ float As[16][68];
    __shared__ float Bs[16][68];
    const int tid = threadIdx.x;
    const int cb = blockIdx.x & 7;
    const int rb = blockIdx.x >> 3;
    const int r0 = rb * 64, c0 = cb * 64;
    const int ra = tid >> 2, kq = tid & 3;
    const int bk = tid >> 4, bq2 = tid & 15;
    const int tx = tid & 15, ty = tid >> 4;
    float acc[4][4];
#pragma unroll
    for (int i = 0; i < 4; ++i)
#pragma unroll
        for (int j = 0; j < 4; ++j) acc[i][j] = 0.0f;

    for (int kt = 0; kt < 512; kt += 16) {
        const float4 av = *(const float4*)(Wsyn + (size_t)(r0 + ra) * 2560 + kt + kq * 4);
        const float4 bv = *(const float4*)(Wao + (size_t)(kt + bk) * 512 + c0 + bq2 * 4);
        __syncthreads();
        As[kq*4+0][ra] = av.x; As[kq*4+1][ra] = av.y; As[kq*4+2][ra] = av.z; As[kq*4+3][ra] = av.w;
        *(float4*)&Bs[bk][bq2*4] = bv;
        __syncthreads();
#pragma unroll
        for (int kk = 0; kk < 16; ++kk) {
            const float4 a4 = *(const float4*)&As[kk][ty*4];
            const float4 b4 = *(const float4*)&Bs[kk][tx*4];
            const float a[4] = {a4.x, a4.y, a4.z, a4.w};
            const float b[4] = {b4.x, b4.y, b4.z, b4.w};
#pragma unroll
            for (int i = 0; i < 4; ++i)
#pragma unroll
                for (int j = 0; j < 4; ++j) acc[i][j] = fmaf(a[i], b[j], acc[i][j]);
        }
    }
#pragma unroll
    for (int i = 0; i < 4; ++i) {
        const int gr = r0 + ty*4 + i;
        uint2 o = { bf2(acc[i][0], acc[i][1]), bf2(acc[i][2], acc[i][3]) };
        *(uint2*)(Wallt + wallt_idx(gr, c0 + tx*4)) = o;
    }
}

// ---------------------------------------------------------------------------
// S1: MFMA bf16 GEMM: C(16384x1024) = gather(emb,tok) @ WinKV^T -> khb/vhb
// ---------------------------------------------------------------------------
__global__ __launch_bounds__(256) void s1_kv_mfma(
    const int* __restrict__ tok, const float* __restrict__ emb,
    const float* __restrict__ Win, const float* __restrict__ b_in,
    unsigned short* __restrict__ khb, unsigned short* __restrict__ vhb)
{
    __shared__ alignas(16) unsigned short SM[17408];
    unsigned short* Al = SM;
    unsigned short* Bl = SM + 8192;
    const int tid = threadIdx.x;
    const int cb = blockIdx.x >> 7;
    const int rb = blockIdx.x & 127;
    const int r0 = rb * 128, c0 = cb * 128;
    int tokrow[8];
#pragma unroll
    for (int j = 0; j < 8; ++j) tokrow[j] = tok[r0 + ((tid + 256 * j) >> 4)];

    const int wid = tid >> 6, lane = tid & 63;
    const int wm = (wid >> 1) * 64, wn = (wid & 1) * 64;
    const int fr = lane & 15;
    const int fkb = (lane >> 4) * 16;
    f32x4 acc[4][4];
#pragma unroll
    for (int i = 0; i < 4; ++i)
#pragma unroll
        for (int j = 0; j < 4; ++j)
#pragma unroll
            for (int e = 0; e < 4; ++e) acc[i][j][e] = 0.0f;

    for (int kt = 0; kt < 512; kt += 64) {
        float4 av[8], bv[8];
#pragma unroll
        for (int j = 0; j < 8; ++j) {
            const int flat = tid + 256 * j;
            const int row = flat >> 4, kq4 = flat & 15;
            av[j] = *(const float4*)(emb + (size_t)tokrow[j] * 512 + kt + kq4 * 4);
            bv[j] = *(const float4*)(Win + (size_t)(512 + c0 + row) * 512 + kt + kq4 * 4);
        }
        __syncthreads();
#pragma unroll
        for (int j = 0; j < 8; ++j) {
            const int flat = tid + 256 * j;
            const int row = flat >> 4, kq4 = flat & 15;
            const int boff = row * 128 + kq4 * 8;
            uint2 pa = { bf2(av[j].x, av[j].y), bf2(av[j].z, av[j].w) };
            uint2 pb = { bf2(bv[j].x, bv[j].y), bf2(bv[j].z, bv[j].w) };
            *(uint2*)((char*)Al + SWZ(boff)) = pa;
            *(uint2*)((char*)Bl + SWZ(boff)) = pb;
        }
        __syncthreads();
#pragma unroll
        for (int ks = 0; ks < 2; ++ks) {
            short8v af[4], bfv[4];
#pragma unroll
            for (int i = 0; i < 4; ++i)
                af[i] = *(const short8v*)((const char*)Al + SWZ((wm + i * 16 + fr) * 128 + ks * 64 + fkb));
#pragma unroll
            for (int j = 0; j < 4; ++j)
                bfv[j] = *(const short8v*)((const char*)Bl + SWZ((wn + j * 16 + fr) * 128 + ks * 64 + fkb));
#pragma unroll
            for (int i = 0; i < 4; ++i)
#pragma unroll
                for (int j = 0; j < 4; ++j)
                    acc[i][j] = __builtin_amdgcn_mfma_f32_16x16x32_bf16(af[i], bfv[j], acc[i][j], 0, 0, 0);
        }
    }
    __syncthreads();
#pragma unroll
    for (int j = 0; j < 4; ++j) {
        const int n = wn + j * 16 + fr;
        const float bias = b_in[512 + c0 + n];
#pragma unroll
        for (int i = 0; i < 4; ++i) {
            const int rbase = wm + i * 16 + (lane >> 4) * 4;
#pragma unroll
            for (int rr = 0; rr < 4; ++rr)
                SM[(rbase + rr) * 136 + n] = bfr(acc[i][j][rr] + bias);
        }
    }
    __syncthreads();
    unsigned short* outbase = (c0 < 512) ? khb : vhb;
    const int ccol = (c0 < 512) ? c0 : (c0 - 512);
    {
        const int orow = tid >> 1, oh = tid & 1;
        unsigned short* gdst = outbase + (size_t)(r0 + orow) * 512 + ccol + oh * 64;
        const unsigned short* lsrc = SM + orow * 136 + oh * 64;
#pragma unroll
        for (int q = 0; q < 8; ++q)
            *(uint4*)(gdst + q * 8) = *(const uint4*)(lsrc + q * 8);
    }
}

// ---------------------------------------------------------------------------
// SETUP2 (after s1): [0,32) s6w: WMt + kmc; [32,544) s6c: khc
// ---------------------------------------------------------------------------
__global__ __launch_bounds__(256) void setup2(
    const float* __restrict__ Win, const float* __restrict__ b_in,
    const unsigned short* __restrict__ Mb, const float* __restrict__ qc0,
    const unsigned short* __restrict__ khb,
    unsigned short* __restrict__ WMt, float* __restrict__ kmc,
    float* __restrict__ khc)
{
    const int tid = threadIdx.x;
    const int bid = blockIdx.x;
    if (bid < 32) {
        __shared__ float Ws[64 * 128];
        __shared__ float Mf[64 * 33];
        __shared__ float bp[64];
        const int h = bid >> 2, ct = bid & 3;
#pragma unroll
        for (int i = 0; i < 8; ++i) {
            const int flat4 = tid + 256 * i;
            const int d = flat4 >> 5, cl4 = flat4 & 31;
            *(float4*)&Ws[d * 128 + cl4 * 4] =
                *(const float4*)(Win + (size_t)(512 + h * 64 + d) * 512 + ct * 128 + cl4 * 4);
        }
#pragma unroll
        for (int i = 0; i < 8; ++i) {
            const int flat = tid + 256 * i;
            const int d = flat >> 5, j2 = flat & 31;
            Mf[d * 33 + j2] = bff(Mb[(size_t)(h * 64 + d) * 32 + j2]);
        }
        if (tid < 64) bp[tid] = b_in[512 + h * 64 + tid];
        __syncthreads();
        const int j = tid & 31, clg = tid >> 5;
        float accw[16];
#pragma unroll
        for (int i = 0; i < 16; ++i) accw[i] = 0.0f;
        for (int d = 0; d < 64; ++d) {
            const float mf = Mf[d * 33 + j];
            const float* wr = &Ws[d * 128 + clg * 16];
#pragma unroll
            for (int i = 0; i < 16; ++i) accw[i] = fmaf(wr[i], mf, accw[i]);
        }
#pragma unroll
        for (int i = 0; i < 16; ++i)
            WMt[(size_t)(h * 32 + j) * 512 + ct * 128 + clg * 16 + i] = bfr(accw[i]);
        if (ct == 0 && clg == 0) {
            float s = 0.0f;
            for (int d = 0; d < 64; ++d) s = fmaf(bp[d], Mf[d * 33 + j], s);
            kmc[h * 32 + j] = s;
        }
    } else {
        __shared__ float qls[512];
        const int sb = bid - 32;
        qls[tid] = qc0[tid];
        qls[tid + 256] = qc0[tid + 256];
        __syncthreads();
        const int h = tid & 7, rl = tid >> 3;
        const int r = sb * 32 + rl;
        const unsigned short* kr = khb + (size_t)r * 512 + h * 64;
        const float* q8 = &qls[h * 64];
        float kc = 0.0f;
#pragma unroll
        for (int i = 0; i < 8; ++i) {
            const uint4 kv = *(const uint4*)(kr + i * 8);
            kc = fmaf(BLO(kv.x), q8[i*8+0], kc); kc = fmaf(BHI(kv.x), q8[i*8+1], kc);
            kc = fmaf(BLO(kv.y), q8[i*8+2], kc); kc = fmaf(BHI(kv.y), q8[i*8+3], kc);
            kc = fmaf(BLO(kv.z), q8[i*8+4], kc); kc = fmaf(BHI(kv.z), q8[i*8+5], kc);
            kc = fmaf(BLO(kv.w), q8[i*8+6], kc); kc = fmaf(BHI(kv.w), q8[i*8+7], kc);
        }
        khc[((size_t)(r >> 9) * 8 + h) * 512 + (r & 511)] = kc;
    }
}

// ---------------------------------------------------------------------------
// S7: MFMA bf16 GEMM: khM(16384 x 256) = gather(emb,tok) @ WMt^T + kmc
// ---------------------------------------------------------------------------
__global__ __launch_bounds__(256) void s7_khm_mfma(
    const int* __restrict__ tok, const float* __restrict__ emb,
    const unsigned short* __restrict__ WMt, const float* __restrict__ kmc,
    unsigned short* __restrict__ khM)
{
    __shared__ alignas(16) unsigned short Al[128 * 64];
    __shared__ alignas(16) unsigned short Bl[128 * 64];
    const int tid = threadIdx.x;
    const int cb = blockIdx.x >> 7;
    const int rb = blockIdx.x & 127;
    const int r0 = rb * 128, c0 = cb * 128;
    int tokrow[8];
#pragma unroll
    for (int j = 0; j < 8; ++j) tokrow[j] = tok[r0 + ((tid + 256 * j) >> 4)];

    const int wid = tid >> 6, lane = tid & 63;
    const int wm = (wid >> 1) * 64, wn = (wid & 1) * 64;
    const int fr = lane & 15;
    const int fkb = (lane >> 4) * 16;
    f32x4 acc[4][4];
#pragma unroll
    for (int i = 0; i < 4; ++i)
#pragma unroll
        for (int j = 0; j < 4; ++j)
#pragma unroll
            for (int e = 0; e < 4; ++e) acc[i][j][e] = 0.0f;

    for (int kt = 0; kt < 512; kt += 64) {
        float4 av[8];
        uint4 bv4[4];
#pragma unroll
        for (int j = 0; j < 8; ++j) {
            const int flat = tid + 256 * j;
            const int row = flat >> 4, kq4 = flat & 15;
            av[j] = *(const float4*)(emb + (size_t)tokrow[j] * 512 + kt + kq4 * 4);
        }
#pragma unroll
        for (int j = 0; j < 4; ++j) {
            const int flat = tid + 256 * j;
            const int row = flat >> 3, kq8 = flat & 7;
            bv4[j] = *(const uint4*)(WMt + (size_t)(c0 + row) * 512 + kt + kq8 * 8);
        }
        __syncthreads();
#pragma unroll
        for (int j = 0; j < 8; ++j) {
            const int flat = tid + 256 * j;
            const int row = flat >> 4, kq4 = flat & 15;
            const int boff = row * 128 + kq4 * 8;
            uint2 pa = { bf2(av[j].x, av[j].y), bf2(av[j].z, av[j].w) };
            *(uint2*)((char*)Al + SWZ(boff)) = pa;
        }
#pragma unroll
        for (int j = 0; j < 4; ++j) {
            const int flat = tid + 256 * j;
            const int row = flat >> 3, kq8 = flat & 7;
            const int boff = row * 128 + kq8 * 16;
            *(uint4*)((char*)Bl + SWZ(boff)) = bv4[j];
        }
        __syncthreads();
#pragma unroll
        for (int ks = 0; ks < 2; ++ks) {
            short8v af[4], bfv[4];
#pragma unroll
            for (int i = 0; i < 4; ++i)
                af[i] = *(const short8v*)((const char*)Al + SWZ((wm + i * 16 + fr) * 128 + ks * 64 + fkb));
#pragma unroll
            for (int j = 0; j < 4; ++j)
                bfv[j] = *(const short8v*)((const char*)Bl + SWZ((wn + j * 16 + fr) * 128 + ks * 64 + fkb));
#pragma unroll
            for (int i = 0; i < 4; ++i)
#pragma unroll
                for (int j = 0; j < 4; ++j)
                    acc[i][j] = __builtin_amdgcn_mfma_f32_16x16x32_bf16(af[i], bfv[j], acc[i][j], 0, 0, 0);
        }
    }
#pragma unroll
    for (int j = 0; j < 4; ++j) {
        const int n = wn + j * 16 + fr;
        const int gc = c0 + n;
        const int h = gc >> 5, jj = gc & 31;
        const float kadd = kmc[gc];
#pragma unroll
        for (int i = 0; i < 4; ++i) {
            const int rbase = wm + i * 16 + (lane >> 4) * 4;
#pragma unroll
            for (int rr = 0; rr < 4; ++rr) {
                const int gr = r0 + rbase + rr;
                khM[(((size_t)(gr >> 9) * 8 + h) * 512 + (gr & 511)) * 32 + jj] =
                    bfr(acc[i][j][rr] + kadd);
            }
        }
    }
}

// ---------------------------------------------------------------------------
// K1: per (b,h), 512 thr: EMA; score = 0.125*(khM.sync + khc); shfl softmax;
// PV from preloaded vh regs -> Abt bf16
// ---------------------------------------------------------------------------
__global__ __launch_bounds__(512) void k1_attn(
    const float* __restrict__ act, const float* __restrict__ decay_a,
    const float* __restrict__ decay_o, const int* __restrict__ ial,
    const int* __restrict__ iar, const int* __restrict__ iol,
    const int* __restrict__ ior,
    const unsigned short* __restrict__ khM, const float* __restrict__ khc,
    const unsigned short* __restrict__ vhb, float* __restrict__ aaB,
    float* __restrict__ baB, float* __restrict__ aoB, float* __restrict__ boB,
    unsigned short* __restrict__ Abt, float* __restrict__ stats, const int u)
{
    __shared__ float sync_lds[32];
    __shared__ float sc[512];
    __shared__ float red[16];
    __shared__ float pvred[512];
    const int tid = threadIdx.x;
    const int b = blockIdx.x >> 3, h = blockIdx.x & 7;

    const size_t mb = (((size_t)b * 8 + h) * 512 + tid) * 32;
    const uint4 km0 = *(const uint4*)(khM + mb);
    const uint4 km1 = *(const uint4*)(khM + mb + 8);
    const uint4 km2 = *(const uint4*)(khM + mb + 16);
    const uint4 km3 = *(const uint4*)(khM + mb + 24);
    const float kc = khc[((size_t)b * 8 + h) * 512 + tid];
    const int l = tid & 63, w = tid >> 6;
    const unsigned short* vb = vhb + ((size_t)(b * 512 + w * 64)) * 512 + h * 64 + l;
    unsigned short vraw[64];
#pragma unroll
    for (int si = 0; si < 64; ++si) vraw[si] = vb[(size_t)si * 512];

    if (tid < 32) {
        const int j = tid;
        const float ra = decf(decay_a[j]);
        const float pa = act[b*2048 + ial[j]] * act[b*2048 + iar[j]];
        const float aa = fmaf(ra, aaB[(u & 1)*1024 + b*32 + j], pa);
        const float ban = fmaf(ra, baB[(u & 1)*1024 + b*32 + j], 1.0f);
        if (h == 0) { aaB[((u+1)&1)*1024 + b*32 + j] = aa; baB[((u+1)&1)*1024 + b*32 + j] = ban; }
        sync_lds[j] = aa * rsqrtf(ban);
    } else if (tid >= 64 && tid < 128) {
        if (u > 0) {
            const int j = tid - 64;
            const float ro = decf(decay_o[j]);
            const float po = act[b*2048 + iol[j]] * act[b*2048 + ior[j]];
            const float ao = fmaf(ro, aoB[((u-1)&1)*2048 + b*64 + j], po);
            const float bo = fmaf(ro, boB[((u-1)&1)*2048 + b*64 + j], 1.0f);
            if (h == 0) { aoB[(u&1)*2048 + b*64 + j] = ao; boB[(u&1)*2048 + b*64 + j] = bo; }
        }
    } else if (tid >= 128 && tid < 192) {
        if (u > 0 && blockIdx.x == 0) stats[tid - 128] = 0.0f;
    }
    __syncthreads();
    float sv = kc;
    {
        const float* sy = sync_lds;
        sv = fmaf(BLO(km0.x), sy[0], sv);  sv = fmaf(BHI(km0.x), sy[1], sv);
        sv = fmaf(BLO(km0.y), sy[2], sv);  sv = fmaf(BHI(km0.y), sy[3], sv);
        sv = fmaf(BLO(km0.z), sy[4], sv);  sv = fmaf(BHI(km0.z), sy[5], sv);
        sv = fmaf(BLO(km0.w), sy[6], sv);  sv = fmaf(BHI(km0.w), sy[7], sv);
        sv = fmaf(BLO(km1.x), sy[8], sv);  sv = fmaf(BHI(km1.x), sy[9], sv);
        sv = fmaf(BLO(km1.y), sy[10], sv); sv = fmaf(BHI(km1.y), sy[11], sv);
        sv = fmaf(BLO(km1.z), sy[12], sv); sv = fmaf(BHI(km1.z), sy[13], sv);
        sv = fmaf(BLO(km1.w), sy[14], sv); sv = fmaf(BHI(km1.w), sy[15], sv);
        sv = fmaf(BLO(km2.x), sy[16], sv); sv = fmaf(BHI(km2.x), sy[17], sv);
        sv = fmaf(BLO(km2.y), sy[18], sv); sv = fmaf(BHI(km2.y), sy[19], sv);
        sv = fmaf(BLO(km2.z), sy[20], sv); sv = fmaf(BHI(km2.z), sy[21], sv);
        sv = fmaf(BLO(km2.w), sy[22], sv); sv = fmaf(BHI(km2.w), sy[23], sv);
        sv = fmaf(BLO(km3.x), sy[24], sv); sv = fmaf(BHI(km3.x), sy[25], sv);
        sv = fmaf(BLO(km3.y), sy[26], sv); sv = fmaf(BHI(km3.y), sy[27], sv);
        sv = fmaf(BLO(km3.z), sy[28], sv); sv = fmaf(BHI(km3.z), sy[29], sv);
        sv = fmaf(BLO(km3.w), sy[30], sv); sv = fmaf(BHI(km3.w), sy[31], sv);
    }
    const float v = sv * 0.125f;
    const int wid = tid >> 6;
    float m = v;
#pragma unroll
    for (int off = 32; off > 0; off >>= 1) m = fmaxf(m, __shfl_xor(m, off));
    if ((tid & 63) == 0) red[wid] = m;
    __syncthreads();
    float mx = red[0];
#pragma unroll
    for (int j = 1; j < 8; ++j) mx = fmaxf(mx, red[j]);
    const float e = __expf(v - mx);
    sc[tid] = e;
    float s = e;
#pragma unroll
    for (int off = 32; off > 0; off >>= 1) s += __shfl_xor(s, off);
    if ((tid & 63) == 0) red[8 + wid] = s;
    __syncthreads();
    float tot = red[8];
#pragma unroll
    for (int j = 1; j < 8; ++j) tot += red[8 + j];
    const float inv = 1.0f / tot;
    {
        float a3 = 0.0f;
#pragma unroll
        for (int si = 0; si < 64; ++si)
            a3 = fmaf(sc[w*64 + si], bff(vraw[si]), a3);
        pvred[w*64 + l] = a3;
    }
    __syncthreads();
    if (tid < 64) {
        float a = 0.0f;
#pragma unroll
        for (int j = 0; j < 8; ++j) a += pvred[j*64 + tid];
        Abt[abt_idx(b, h*64 + tid)] = bfr(a * inv);
    }
}

// ---------------------------------------------------------------------------
// K2b: synapse via MFMA, 1024 thr / 16-way K-split -> GLU -> sg; LN stats
// ---------------------------------------------------------------------------
__global__ __launch_bounds__(1024) void k2b_syn(
    const unsigned short* __restrict__ Abt, const unsigned short* __restrict__ Wallt,
    const float* __restrict__ bsyn2, float* __restrict__ sg, float* __restrict__ stats)
{
    __shared__ float part[16 * 512];   // 32 KB
    const int tid = threadIdx.x;
    const int c0 = blockIdx.x * 8;
    const int w = tid >> 6, lane = tid & 63, fr = lane & 15, kq = lane >> 4;
    const int kb0 = w * 20 + kq;
    const unsigned short* wrow = Wallt + (((size_t)blockIdx.x * 320 + kb0) * 16 + fr) * 8;
    const unsigned short* ar0 = Abt + (((size_t)kb0) * 32 + fr) * 8;
    const unsigned short* ar1 = ar0 + 128;
    f32x4 acc0 = {0.f,0.f,0.f,0.f}, acc1 = {0.f,0.f,0.f,0.f};
#pragma unroll
    for (int kk = 0; kk < 5; ++kk) {
        const short8v bfrag = *(const short8v*)(wrow + kk*512);
        const short8v a0f = *(const short8v*)(ar0 + kk*1024);
        const short8v a1f = *(const short8v*)(ar1 + kk*1024);
        acc0 = __builtin_amdgcn_mfma_f32_16x16x32_bf16(a0f, bfrag, acc0, 0, 0, 0);
        acc1 = __builtin_amdgcn_mfma_f32_16x16x32_bf16(a1f, bfrag, acc1, 0, 0, 0);
    }
#pragma unroll
    for (int r = 0; r < 4; ++r) {
        part[w*512 + (kq*4 + r)*16 + fr] = acc0[r];
        part[w*512 + 256 + (kq*4 + r)*16 + fr] = acc1[r];
    }
    __syncthreads();
    if (tid < 512) {
        float rs = 0.0f;
#pragma unroll
        for (int w2 = 0; w2 < 16; ++w2) rs += part[w2*512 + tid];
        const float other = __shfl_xor(rs, 8);
        const int coli = tid & 15;
        const int m = ((tid >> 8) << 4) | ((tid >> 4) & 15);
        float gval = 0.0f;
        if (coli < 8) {
            const int c = c0 + coli;
            const float va = rs + bsyn2[c];
            const float vg = other + bsyn2[2048 + c];
            gval = va * sigf(vg);
            sg[m*2048 + c] = gval;
        }
        float s1 = gval, s2v = gval*gval;
        s1 += __shfl_xor(s1, 1); s2v += __shfl_xor(s2v, 1);
        s1 += __shfl_xor(s1, 2); s2v += __shfl_xor(s2v, 2);
        s1 += __shfl_xor(s1, 4); s2v += __shfl_xor(s2v, 4);
        if (coli == 0) {
            atomicAdd(&stats[m*2],     s1);
            atomicAdd(&stats[m*2 + 1], s2v);
        }
    }
}

// ---------------------------------------------------------------------------
// K3: LN + trace + per-neuron NLM -> act (+Abt). grid 1024 (2 neurons), 256 thr
// ---------------------------------------------------------------------------
__global__ __launch_bounds__(256) void k3_nlm(
    const float* __restrict__ sg, const float* __restrict__ stats,
    const float* __restrict__ ln_g, const float* __restrict__ ln_b,
    const unsigned short* __restrict__ W1t, const unsigned short* __restrict__ W2t,
    const float* __restrict__ b2,
    float* __restrict__ trace, float* __restrict__ act,
    unsigned short* __restrict__ Abt, const int u)
{
    __shared__ float tr[64 * 12];
    __shared__ float pk[64 * 133];
    const int tid = threadIdx.x;
    const int n0 = blockIdx.x * 2;
    if (tid < 64) {
        const int bb = tid >> 1, nl0 = tid & 1;
        const int n = n0 + nl0;
        float* trow = &tr[tid * 12];
#pragma unroll
        for (int m = 0; m < 9; ++m) {
            const int slot = (u + 1 + m) % 10;
            trow[m] = trace[(bb*10 + slot)*2048 + n];
        }
        const float mean = stats[bb*2] * (1.0f/2048.0f);
        const float var  = stats[bb*2+1] * (1.0f/2048.0f) - mean*mean;
        const float rstd = rsqrtf(var + 1e-5f);
        const float v9 = (sg[bb*2048 + n] - mean) * rstd * ln_g[n] + ln_b[n];
        trow[9] = v9;
        trace[(bb*10 + (u % 10))*2048 + n] = v9;
    }
    const int nl = tid & 1, hg = (tid >> 1) & 63, bh = tid >> 7;
    float w1a[10], w1g[10], b1a, b1g, w2v0, w2v1;
    {
        const unsigned short* pa = W1t + (((size_t)blockIdx.x*128 + hg)*2 + nl)*16;
        const uint4 qa = *(const uint4*)pa;
        const uint4 qb = *(const uint4*)(pa + 8);
        w1a[0] = BLO(qa.x); w1a[1] = BHI(qa.x); w1a[2] = BLO(qa.y); w1a[3] = BHI(qa.y);
        w1a[4] = BLO(qa.z); w1a[5] = BHI(qa.z); w1a[6] = BLO(qa.w); w1a[7] = BHI(qa.w);
        w1a[8] = BLO(qb.x); w1a[9] = BHI(qb.x); b1a = BLO(qb.y);
        const unsigned short* pg = W1t + (((size_t)blockIdx.x*128 + 64 + hg)*2 + nl)*16;
        const uint4 ra = *(const uint4*)pg;
        const uint4 rb = *(const uint4*)(pg + 8);
        w1g[0] = BLO(ra.x); w1g[1] = BHI(ra.x); w1g[2] = BLO(ra.y); w1g[3] = BHI(ra.y);
        w1g[4] = BLO(ra.z); w1g[5] = BHI(ra.z); w1g[6] = BLO(ra.w); w1g[7] = BHI(ra.w);
        w1g[8] = BLO(rb.x); w1g[9] = BHI(rb.x); b1g = BLO(rb.y);
        const unsigned int q2 = *(const unsigned int*)(W2t + (((size_t)blockIdx.x*64 + hg)*2 + nl)*2);
        w2v0 = BLO(q2); w2v1 = BHI(q2);
    }
    __syncthreads();
#pragma unroll
    for (int bi = 0; bi < 16; ++bi) {
        const int bb = bh * 16 + bi;
        const float* trow = &tr[(bb*2 + nl)*12];
        const float4 t0 = *(const float4*)trow;
        const float4 t1 = *(const float4*)(trow + 4);
        const float2 t2 = *(const float2*)(trow + 8);
        const float t[10] = {t0.x,t0.y,t0.z,t0.w,t1.x,t1.y,t1.z,t1.w,t2.x,t2.y};
        float ha = b1a, hgv = b1g;
#pragma unroll
        for (int mm = 0; mm < 10; ++mm) {
            ha  = fmaf(t[mm], w1a[mm], ha);
            hgv = fmaf(t[mm], w1g[mm], hgv);
        }
        const float g0 = ha * sigf(hgv);
        pk[hg*133 + bb*4 + nl*2 + 0] = g0 * w2v0;
        pk[hg*133 + bb*4 + nl*2 + 1] = g0 * w2v1;
    }
    __syncthreads();
    if (tid < 128) {
        const int obb = tid >> 2, onl = (tid >> 1) & 1, oo = tid & 1;
        float rs = 0.0f;
#pragma unroll 8
        for (int q = 0; q < 64; ++q) rs += pk[q*133 + tid];
        rs += b2[(n0 + onl)*2 + oo];
        const float h2o = __shfl_xor(rs, 1);
        if (oo == 0) {
            const float actv = rs * sigf(h2o);
            act[obb*2048 + n0 + onl] = actv;
            Abt[abt_idx(obb, 512 + n0 + onl)] = bfr(actv);
        }
    }
}

// ---------------------------------------------------------------------------
// K4: final o-update, sync_o, ratings, cert
// ---------------------------------------------------------------------------
__global__ __launch_bounds__(256) void k4_final(
    const float* __restrict__ aoB, const float* __restrict__ boB,
    const float* __restrict__ act, const float* __restrict__ decay_o,
    const int* __restrict__ iol, const int* __restrict__ ior,
    const float* __restrict__ Wout, const float* __restrict__ bout,
    float* __restrict__ out)
{
    __shared__ float sl[2048];
    const int tid = threadIdx.x;
    for (int idx = tid; idx < 2048; idx += 256) {
        const int b = idx >> 6, j = idx & 63;
        const float ro = decf(decay_o[j]);
        const float po = act[b*2048 + iol[j]] * act[b*2048 + ior[j]];
        const float ao = fmaf(ro, aoB[2048 + b*64 + j], po);
        const float bo = fmaf(ro, boB[2048 + b*64 + j], 1.0f);
        const float sv = ao * rsqrtf(bo);
        sl[idx] = sv;
        out[96 + idx] = sv;
    }
    __syncthreads();
    if (tid < 32) {
        float p = bout[0];
        for (int j = 0; j < 64; ++j) p = fmaf(sl[tid*64 + j], Wout[j], p);
        out[tid] = sigf(p);
    } else if (tid < 96) {
        out[32 + (tid - 32)] = ((tid - 32) & 1) ? 1.0f : 0.0f;
    }
}

// ---------------------------------------------------------------------------
extern "C" void kernel_launch(void* const* d_in, const int* in_sizes, int n_in,
                              void* d_out, int out_size, void* d_ws, size_t ws_size,
                              hipStream_t stream)
{
    (void)in_sizes; (void)n_in; (void)out_size;
    const int*   tok   = (const int*)  d_in[0];
    const float* emb   = (const float*)d_in[1];
    const float* st_tr = (const float*)d_in[2];
    const float* st_ac = (const float*)d_in[3];
    const float* dec_a = (const float*)d_in[4];
    const float* dec_o = (const float*)d_in[5];
    const int*   ial   = (const int*)  d_in[6];
    const int*   iar   = (const int*)  d_in[7];
    const int*   iol   = (const int*)  d_in[8];
    const int*   ior   = (const int*)  d_in[9];
    const float* Wq    = (const float*)d_in[10];
    const float* bq    = (const float*)d_in[11];
    const float* Win   = (const float*)d_in[12];
    const float* b_in  = (const float*)d_in[13];
    const float* Wao   = (const float*)d_in[14];
    const float* bao   = (const float*)d_in[15];
    const float* Wsyn  = (const float*)d_in[16];
    const float* bsyn  = (const float*)d_in[17];
    const float* ln_g  = (const float*)d_in[18];
    const float* ln_b  = (const float*)d_in[19];
    const float* W1    = (const float*)d_in[20];
    const float* b1    = (const float*)d_in[21];
    const float* W2    = (const float*)d_in[22];
    const float* b2    = (const float*)d_in[23];
    const float* Wout  = (const float*)d_in[24];
    const float* bout  = (const float*)d_in[25];
    float* out = (float*)d_out;
    char* wsb = (char*)d_ws;
    if (ws_size < (size_t)76025088) return;
    unsigned short* khb   = (unsigned short*)(wsb + 0);          // 16 MB
    unsigned short* vhb   = (unsigned short*)(wsb + 16777216);   // 16 MB
    unsigned short* Wallt = (unsigned short*)(wsb + 33554432);   // 20 MB
    unsigned short* W1t   = (unsigned short*)(wsb + 54525952);   // 8 MB
    unsigned short* W2t   = (unsigned short*)(wsb + 62914560);   // 512 KB
    unsigned short* khM   = (unsigned short*)(wsb + 63438848);   // 8 MB
    float* khc  = (float*)(wsb + 71827456);                      // 512 KB
    unsigned short* Mb    = (unsigned short*)(wsb + 72351744);   // 32 KB
    float* qc0  = (float*)(wsb + 72384512);                      // 2 KB
    float* trace = (float*)(wsb + 72386560);                     // 2.5 MB
    float* actb  = (float*)(wsb + 75008000);                     // 256 KB
    float* sg    = (float*)(wsb + 75270144);                     // 256 KB
    unsigned short* Abt = (unsigned short*)(wsb + 75532288);     // 160 KB
    float* aaB   = (float*)(wsb + 75696128);
    float* baB   = (float*)(wsb + 75704320);
    float* aoB   = (float*)(wsb + 75712512);
    float* boB   = (float*)(wsb + 75728896);
    float* bs2   = (float*)(wsb + 75745280);
    float* stats = (float*)(wsb + 75761664);
    unsigned short* WMt = (unsigned short*)(wsb + 75761920);     // 256 KB
    float* kmc  = (float*)(wsb + 76024064);                      // 1 KB

    setup1<<<dim3(4201), dim3(256), 0, stream>>>(
        st_tr, st_ac, iol, ior, trace, actb, Abt, aaB, baB, aoB, boB, stats,
        Wsyn, Wallt, bao, bsyn, bs2, W1, b1, W2, W1t, W2t,
        Win, b_in, Wq, bq, Mb, qc0);
    s2_wfused<<<dim3(512), dim3(256), 0, stream>>>(Wsyn, Wao, Wallt);
    s1_kv_mfma<<<dim3(1024), dim3(256), 0, stream>>>(tok, emb, Win, b_in, khb, vhb);
    setup2<<<dim3(544), dim3(256), 0, stream>>>(Win, b_in, Mb, qc0, khb, WMt, kmc, khc);
    s7_khm_mfma<<<dim3(256), dim3(256), 0, stream>>>(tok, emb, WMt, kmc, khM);
    for (int u = 0; u < 20; ++u) {
        k1_attn<<<dim3(256), dim3(512), 0, stream>>>(actb, dec_a, dec_o,
            ial, iar, iol, ior, khM, khc, vhb,
            aaB, baB, aoB, boB, Abt, stats, u);
        k2b_syn<<<dim3(256), dim3(1024), 0, stream>>>(Abt, Wallt, bs2, sg, stats);
        k3_nlm<<<dim3(1024), dim3(256), 0, stream>>>(sg, stats, ln_g, ln_b,
            W1t, W2t, b2, trace, actb, Abt, u);
    }
    k4_final<<<dim3(1), dim3(256), 0, stream>>>(aoB, boB, actb, dec_o,
        iol, ior, Wout, bout, out);
}